// Round 2
// baseline (55.857 us; speedup 1.0000x reference)
//
#include <hip/hip_runtime.h>
#include <stdint.h>

#define BATCH   1024
#define IDIM    4096
#define NLUTS   16384

// ---- main kernel geometry ----
#define TPB     512
#define NT      4                  // n's per thread
#define NPB     (TPB * NT)         // 2048
#define NBLK_N  (NLUTS / NPB)      // 8
#define BT      2                  // batch rows per LDS tile (ds_read_b64 gather)
#define G       4                  // groups (tiles) per block
#define ROWS    (BT * G)           // 8 rows per block
#define NBLK_B  (BATCH / ROWS)     // 128
#define GRID    (NBLK_N * NBLK_B)  // 1024

typedef __attribute__((address_space(3))) uint32_t lds_u32;
typedef __attribute__((address_space(1))) uint32_t gbl_u32;

// ---------------- coefficient pre-kernel ----------------
// a[n][mask]: monomial coefficients of the multilinear form, from
// s = sigmoid(w - wc) reversed + 4-level butterfly (p0,p1)->(p1,p0-p1).
__global__ void coeff_kernel(const float* __restrict__ w,
                             const float* __restrict__ wc,
                             float* __restrict__ cf)
{
    int n = blockIdx.x * 64 + threadIdx.x;   // grid = 256 x 64
    float p[16];
#pragma unroll
    for (int k = 0; k < 4; ++k) {
        float4 wv = *reinterpret_cast<const float4*>(w  + (size_t)n * 16 + 4 * k);
        float4 cv = *reinterpret_cast<const float4*>(wc + (size_t)n * 16 + 4 * k);
        p[15 - (4 * k + 0)] = 1.f / (1.f + __expf(cv.x - wv.x));
        p[15 - (4 * k + 1)] = 1.f / (1.f + __expf(cv.y - wv.y));
        p[15 - (4 * k + 2)] = 1.f / (1.f + __expf(cv.z - wv.z));
        p[15 - (4 * k + 3)] = 1.f / (1.f + __expf(cv.w - wv.w));
    }
#pragma unroll
    for (int s = 8; s >= 1; s >>= 1) {
#pragma unroll
        for (int m = 0; m < 16; ++m) {
            if ((m & s) == 0) { float t0 = p[m]; p[m] = p[m + s]; p[m + s] = t0 - p[m + s]; }
        }
    }
#pragma unroll
    for (int k = 0; k < 4; ++k) {
        float4 o; o.x = p[4*k]; o.y = p[4*k+1]; o.z = p[4*k+2]; o.w = p[4*k+3];
        *reinterpret_cast<float4*>(cf + (size_t)n * 16 + 4 * k) = o;
    }
}

// ---------------- main kernel ----------------
__global__ __launch_bounds__(TPB, 4)
void lut_main(const float* __restrict__ x,
              const float* __restrict__ cf,
              const int*   __restrict__ indices,
              float* __restrict__ out)
{
    // transposed tile: xs[buf][col*2 + rowparity], double-buffered, 2x32KB
    __shared__ float xs[2][IDIM * BT];

    // XCD swizzle: all 8 n-blocks of a b-range land on one XCD -> x rows
    // L2-resident per XCD (16 b-ranges x 8 rows x 16KB = 2 MiB).
    int id    = blockIdx.x;
    int xcd   = id & 7;
    int local = id >> 3;                  // 0..127
    int b_blk = xcd * 16 + (local & 15);  // 0..127
    int n_blk = local >> 4;               // 0..7

    int t  = threadIdx.x;
    int wv = t >> 6;
    int ln = t & 63;
    int n0 = n_blk * NPB + t * NT;
    int b0 = b_blk * ROWS;

    // per-thread LUT indices
    int ix[NT][4];
#pragma unroll
    for (int i = 0; i < 4; ++i) {
        int4 v = *reinterpret_cast<const int4*>(indices + i * NLUTS + n0);
        ix[0][i] = v.x; ix[1][i] = v.y; ix[2][i] = v.z; ix[3][i] = v.w;
    }

    // per-thread monomial coefficients (precomputed, 1 MiB L2/L3-hot)
    float a[NT][16];
#pragma unroll
    for (int q = 0; q < NT; ++q) {
#pragma unroll
        for (int k = 0; k < 4; ++k) {
            float4 v = *reinterpret_cast<const float4*>(cf + (size_t)(n0 + q) * 16 + 4 * k);
            a[q][4*k] = v.x; a[q][4*k+1] = v.y; a[q][4*k+2] = v.z; a[q][4*k+3] = v.w;
        }
    }

    // global_load_lds staging: LDS word W = wv*1024 + h*64 + lane must hold
    // x[r0 + (W&1)][W>>1]. LDS dest is wave-uniform base + lane*4 (linear);
    // the per-lane GLOBAL address carries the transpose (m173 pattern).
    int colbase = wv * 512 + (ln >> 1);
    int par     = ln & 1;

    auto stage = [&](int buf, int g) {
        const float* src = x + (size_t)(b0 + g * BT + par) * IDIM + colbase;
        float*       dst = &xs[buf][wv * 1024];
#pragma unroll
        for (int h = 0; h < 16; ++h) {
            __builtin_amdgcn_global_load_lds((const gbl_u32*)(src + h * 32),
                                             (lds_u32*)(dst + h * 64), 4, 0, 0);
        }
    };

    stage(0, 0);
    __syncthreads();   // drains vmcnt(0) before barrier -> buf0 ready

#pragma unroll
    for (int g = 0; g < G; ++g) {
        int cur = g & 1;
        if (g + 1 < G) stage(cur ^ 1, g + 1);   // in flight during compute

        float res[NT][BT];
#pragma unroll
        for (int q = 0; q < NT; ++q) {
            float2 xv0 = *reinterpret_cast<const float2*>(&xs[cur][ix[q][0] * 2]);
            float2 xv1 = *reinterpret_cast<const float2*>(&xs[cur][ix[q][1] * 2]);
            float2 xv2 = *reinterpret_cast<const float2*>(&xs[cur][ix[q][2] * 2]);
            float2 xv3 = *reinterpret_cast<const float2*>(&xs[cur][ix[q][3] * 2]);
#pragma unroll
            for (int b = 0; b < BT; ++b) {
                float v0 = b ? xv0.y : xv0.x;
                float v1 = b ? xv1.y : xv1.x;
                float v2 = b ? xv2.y : xv2.x;
                float v3 = b ? xv3.y : xv3.x;
                float h0 = fmaf(v3, a[q][1],  a[q][0]);
                float h1 = fmaf(v3, a[q][3],  a[q][2]);
                float h2 = fmaf(v3, a[q][5],  a[q][4]);
                float h3 = fmaf(v3, a[q][7],  a[q][6]);
                float h4 = fmaf(v3, a[q][9],  a[q][8]);
                float h5 = fmaf(v3, a[q][11], a[q][10]);
                float h6 = fmaf(v3, a[q][13], a[q][12]);
                float h7 = fmaf(v3, a[q][15], a[q][14]);
                float g0 = fmaf(v2, h1, h0);
                float g1 = fmaf(v2, h3, h2);
                float g2 = fmaf(v2, h5, h4);
                float g3 = fmaf(v2, h7, h6);
                float f0 = fmaf(v1, g1, g0);
                float f1 = fmaf(v1, g3, g2);
                res[q][b] = fmaf(v0, f1, f0);
            }
        }

        size_t rbase = (size_t)(b0 + g * BT) * NLUTS + n0;
        float4 o0; o0.x = res[0][0]; o0.y = res[1][0]; o0.z = res[2][0]; o0.w = res[3][0];
        float4 o1; o1.x = res[0][1]; o1.y = res[1][1]; o1.z = res[2][1]; o1.w = res[3][1];
        *reinterpret_cast<float4*>(out + rbase)         = o0;
        *reinterpret_cast<float4*>(out + rbase + NLUTS) = o1;

        __syncthreads();   // all reads of buf[cur] done + next-stage gll drained
    }
}

// ---------------- fallback (round-1 fused kernel, used only if ws too small) ----------------
#define F_TPB   256
#define F_NT    4
#define F_NPB   (F_TPB * F_NT)
#define F_NBLKN (NLUTS / F_NPB)
#define F_BTILE 16
#define F_GRID  (F_NBLKN * (BATCH / F_BTILE))

__global__ __launch_bounds__(F_TPB, 4)
void lut_fused(const float* __restrict__ x, const float* __restrict__ w,
               const float* __restrict__ wcomp, const int* __restrict__ indices,
               float* __restrict__ out)
{
    __shared__ float xsf[2][IDIM];
    int id = blockIdx.x;
    int swz = (id & 7) * (F_GRID / 8) + (id >> 3);
    int b_blk = swz / F_NBLKN, n_blk = swz % F_NBLKN;
    int t = threadIdx.x;
    int n0 = n_blk * F_NPB + t * F_NT;
    int b0 = b_blk * F_BTILE;
    int ix[F_NT][4];
#pragma unroll
    for (int i = 0; i < 4; ++i) {
        int4 v = *reinterpret_cast<const int4*>(indices + i * NLUTS + n0);
        ix[0][i] = v.x; ix[1][i] = v.y; ix[2][i] = v.z; ix[3][i] = v.w;
    }
    float a[F_NT][16];
#pragma unroll
    for (int q = 0; q < F_NT; ++q) {
        int n = n0 + q; float p[16];
#pragma unroll
        for (int k = 0; k < 4; ++k) {
            float4 wv = *reinterpret_cast<const float4*>(w     + (size_t)n * 16 + k * 4);
            float4 cv = *reinterpret_cast<const float4*>(wcomp + (size_t)n * 16 + k * 4);
            p[15-(4*k+0)] = 1.f/(1.f+__expf(cv.x-wv.x));
            p[15-(4*k+1)] = 1.f/(1.f+__expf(cv.y-wv.y));
            p[15-(4*k+2)] = 1.f/(1.f+__expf(cv.z-wv.z));
            p[15-(4*k+3)] = 1.f/(1.f+__expf(cv.w-wv.w));
        }
#pragma unroll
        for (int s = 8; s >= 1; s >>= 1)
#pragma unroll
            for (int m = 0; m < 16; ++m)
                if ((m & s) == 0) { float t0 = p[m]; p[m] = p[m+s]; p[m+s] = t0 - p[m+s]; }
#pragma unroll
        for (int m = 0; m < 16; ++m) a[q][m] = p[m];
    }
    {
        const float* xrow = x + (size_t)b0 * IDIM;
#pragma unroll
        for (int k = 0; k < 4; ++k)
            *reinterpret_cast<float4*>(&xsf[0][(k*F_TPB+t)*4]) =
                *reinterpret_cast<const float4*>(xrow + (k*F_TPB+t)*4);
    }
    __syncthreads();
    for (int bi = 0; bi < F_BTILE; ++bi) {
        int cur = bi & 1; bool more = (bi + 1 < F_BTILE);
        float4 r[4];
        if (more) {
            const float* xrow = x + (size_t)(b0+bi+1) * IDIM;
#pragma unroll
            for (int k = 0; k < 4; ++k)
                r[k] = *reinterpret_cast<const float4*>(xrow + (k*F_TPB+t)*4);
        }
        float res[F_NT];
#pragma unroll
        for (int q = 0; q < F_NT; ++q) {
            float v0 = xsf[cur][ix[q][0]], v1 = xsf[cur][ix[q][1]];
            float v2 = xsf[cur][ix[q][2]], v3 = xsf[cur][ix[q][3]];
            float h0 = fmaf(v3,a[q][1],a[q][0]),  h1 = fmaf(v3,a[q][3],a[q][2]);
            float h2 = fmaf(v3,a[q][5],a[q][4]),  h3 = fmaf(v3,a[q][7],a[q][6]);
            float h4 = fmaf(v3,a[q][9],a[q][8]),  h5 = fmaf(v3,a[q][11],a[q][10]);
            float h6 = fmaf(v3,a[q][13],a[q][12]),h7 = fmaf(v3,a[q][15],a[q][14]);
            float g0 = fmaf(v2,h1,h0), g1 = fmaf(v2,h3,h2);
            float g2 = fmaf(v2,h5,h4), g3 = fmaf(v2,h7,h6);
            res[q] = fmaf(v0, fmaf(v1,g3,g2), fmaf(v1,g1,g0));
        }
        float4 o; o.x=res[0]; o.y=res[1]; o.z=res[2]; o.w=res[3];
        *reinterpret_cast<float4*>(out + (size_t)(b0+bi)*NLUTS + n0) = o;
        if (more) {
            int nxt = cur ^ 1;
#pragma unroll
            for (int k = 0; k < 4; ++k)
                *reinterpret_cast<float4*>(&xsf[nxt][(k*F_TPB+t)*4]) = r[k];
        }
        __syncthreads();
    }
}

extern "C" void kernel_launch(void* const* d_in, const int* in_sizes, int n_in,
                              void* d_out, int out_size, void* d_ws, size_t ws_size,
                              hipStream_t stream) {
    const float* x   = (const float*)d_in[0];
    const float* w   = (const float*)d_in[1];
    const float* wc  = (const float*)d_in[2];
    const int*   idx = (const int*)d_in[3];
    float*       out = (float*)d_out;

    if (ws_size >= (size_t)NLUTS * 16 * sizeof(float)) {
        float* cf = (float*)d_ws;
        coeff_kernel<<<dim3(NLUTS / 64), dim3(64), 0, stream>>>(w, wc, cf);
        lut_main<<<dim3(GRID), dim3(TPB), 0, stream>>>(x, cf, idx, out);
    } else {
        lut_fused<<<dim3(F_GRID), dim3(F_TPB), 0, stream>>>(x, w, wc, idx, out);
    }
}

// Round 3
// 42.253 us; speedup vs baseline: 1.3219x; 1.3219x over previous
//
#include <hip/hip_runtime.h>
#include <stdint.h>

#define BATCH   1024
#define IDIM    4096
#define NLUTS   16384

// ---- main kernel geometry ----
#define TPB     512
#define NT      2                  // n's per thread
#define NPB     (TPB * NT)         // 1024
#define NBLK_N  (NLUTS / NPB)      // 16
#define BT      4                  // batch rows per tile -> ds_read_b128 gather
#define TILES   2                  // tiles per block
#define ROWS    (BT * TILES)       // 8 rows per block
#define NBLK_B  (BATCH / ROWS)     // 128
#define GRID    (NBLK_N * NBLK_B)  // 2048

// ---------------- coefficient pre-kernel ----------------
// a[n][mask]: monomial coefficients of the multilinear form, from
// s = sigmoid(w - wc) reversed + 4-level butterfly (p0,p1)->(p1,p0-p1).
__global__ void coeff_kernel(const float* __restrict__ w,
                             const float* __restrict__ wc,
                             float* __restrict__ cf)
{
    int n = blockIdx.x * 64 + threadIdx.x;   // grid = 256 x 64
    float p[16];
#pragma unroll
    for (int k = 0; k < 4; ++k) {
        float4 wv = *reinterpret_cast<const float4*>(w  + (size_t)n * 16 + 4 * k);
        float4 cv = *reinterpret_cast<const float4*>(wc + (size_t)n * 16 + 4 * k);
        p[15 - (4 * k + 0)] = 1.f / (1.f + __expf(cv.x - wv.x));
        p[15 - (4 * k + 1)] = 1.f / (1.f + __expf(cv.y - wv.y));
        p[15 - (4 * k + 2)] = 1.f / (1.f + __expf(cv.z - wv.z));
        p[15 - (4 * k + 3)] = 1.f / (1.f + __expf(cv.w - wv.w));
    }
#pragma unroll
    for (int s = 8; s >= 1; s >>= 1) {
#pragma unroll
        for (int m = 0; m < 16; ++m) {
            if ((m & s) == 0) { float t0 = p[m]; p[m] = p[m + s]; p[m + s] = t0 - p[m + s]; }
        }
    }
#pragma unroll
    for (int k = 0; k < 4; ++k) {
        float4 o; o.x = p[4*k]; o.y = p[4*k+1]; o.z = p[4*k+2]; o.w = p[4*k+3];
        *reinterpret_cast<float4*>(cf + (size_t)n * 16 + 4 * k) = o;
    }
}

// ---------------- main kernel ----------------
__global__ __launch_bounds__(TPB, 4)
void lut_main(const float* __restrict__ x,
              const float* __restrict__ cf,
              const int*   __restrict__ indices,
              float* __restrict__ out)
{
    // transposed tile: xt[col*4 + r] holds x[b0+tile*4+r][col]. 64 KB, single buf.
    __shared__ float xt[IDIM * BT];

    // XCD swizzle: for each XCD, 16 consecutive blocks share one b-range
    // (all 16 n-blocks) -> the 8 staged x rows are L2-hot on that XCD.
    int id    = blockIdx.x;
    int xcd   = id & 7;
    int k     = id >> 3;                 // 0..255
    int n_blk = k & 15;                  // varies fastest -> same b-range
    int b_blk = (k >> 4) * 8 + xcd;      // 0..127, bijective
    int t     = threadIdx.x;
    int n0    = n_blk * NPB + t * NT;
    int b0    = b_blk * ROWS;

    // per-thread LUT indices: ix[q][i] = indices[i][n0+q]
    int ix[NT][4];
#pragma unroll
    for (int i = 0; i < 4; ++i) {
        int2 v = *reinterpret_cast<const int2*>(indices + i * NLUTS + n0);
        ix[0][i] = v.x; ix[1][i] = v.y;
    }

    // per-thread monomial coefficients (precomputed, 1 MiB, L2-hot)
    float a[NT][16];
#pragma unroll
    for (int q = 0; q < NT; ++q) {
#pragma unroll
        for (int kk = 0; kk < 4; ++kk) {
            float4 v = *reinterpret_cast<const float4*>(cf + (size_t)(n0 + q) * 16 + 4 * kk);
            a[q][4*kk] = v.x; a[q][4*kk+1] = v.y; a[q][4*kk+2] = v.z; a[q][4*kk+3] = v.w;
        }
    }

    // staging registers: thread owns cols c = t + 512*h, h=0..7; 4 rows each.
    // Global loads: lanes consecutive -> 256B coalesced per instruction.
    // LDS writes: ds_write_b128 at col*16B -> bank quad 4*(t&7) covers all 8
    // slots across a wave -> conflict-free (minimum 8 cyc).
    float st[32];

    auto load_tile = [&](int g) {
        const float* xb = x + (size_t)(b0 + g * BT) * IDIM;
#pragma unroll
        for (int h = 0; h < 8; ++h) {
#pragma unroll
            for (int r = 0; r < 4; ++r)
                st[h * 4 + r] = xb[(size_t)r * IDIM + h * 512 + t];
        }
    };
    auto write_tile = [&]() {
#pragma unroll
        for (int h = 0; h < 8; ++h) {
            float4 v; v.x = st[h*4+0]; v.y = st[h*4+1]; v.z = st[h*4+2]; v.w = st[h*4+3];
            *reinterpret_cast<float4*>(&xt[(h * 512 + t) * 4]) = v;
        }
    };

    load_tile(0);
    write_tile();
    __syncthreads();

#pragma unroll
    for (int g = 0; g < TILES; ++g) {
        if (g + 1 < TILES) load_tile(g + 1);   // prefetch next tile into regs

        // compute: per q, 4 b128 gathers (one per LUT input, 4 rows each)
        float res[NT][BT];
#pragma unroll
        for (int q = 0; q < NT; ++q) {
            float c[4][4];
#pragma unroll
            for (int i = 0; i < 4; ++i) {
                float4 v = *reinterpret_cast<const float4*>(&xt[ix[q][i] * 4]);
                c[i][0] = v.x; c[i][1] = v.y; c[i][2] = v.z; c[i][3] = v.w;
            }
#pragma unroll
            for (int r = 0; r < BT; ++r) {
                float v0 = c[0][r], v1 = c[1][r], v2 = c[2][r], v3 = c[3][r];
                float h0 = fmaf(v3, a[q][1],  a[q][0]);
                float h1 = fmaf(v3, a[q][3],  a[q][2]);
                float h2 = fmaf(v3, a[q][5],  a[q][4]);
                float h3 = fmaf(v3, a[q][7],  a[q][6]);
                float h4 = fmaf(v3, a[q][9],  a[q][8]);
                float h5 = fmaf(v3, a[q][11], a[q][10]);
                float h6 = fmaf(v3, a[q][13], a[q][12]);
                float h7 = fmaf(v3, a[q][15], a[q][14]);
                float g0 = fmaf(v2, h1, h0);
                float g1 = fmaf(v2, h3, h2);
                float g2 = fmaf(v2, h5, h4);
                float g3 = fmaf(v2, h7, h6);
                float f0 = fmaf(v1, g1, g0);
                float f1 = fmaf(v1, g3, g2);
                res[q][r] = fmaf(v0, f1, f0);
            }
        }

        // coalesced float2 stores: 4 rows x (2 consecutive n per thread)
#pragma unroll
        for (int r = 0; r < BT; ++r) {
            float2 o; o.x = res[0][r]; o.y = res[1][r];
            *reinterpret_cast<float2*>(out + (size_t)(b0 + g * BT + r) * NLUTS + n0) = o;
        }

        __syncthreads();                       // all reads of xt done
        if (g + 1 < TILES) {
            write_tile();                      // overwrite with prefetched tile
            __syncthreads();
        }
    }
}

// ---------------- fallback (round-1 fused kernel, used only if ws too small) ----------------
#define F_TPB   256
#define F_NT    4
#define F_NPB   (F_TPB * F_NT)
#define F_NBLKN (NLUTS / F_NPB)
#define F_BTILE 16
#define F_GRID  (F_NBLKN * (BATCH / F_BTILE))

__global__ __launch_bounds__(F_TPB, 4)
void lut_fused(const float* __restrict__ x, const float* __restrict__ w,
               const float* __restrict__ wcomp, const int* __restrict__ indices,
               float* __restrict__ out)
{
    __shared__ float xsf[2][IDIM];
    int id = blockIdx.x;
    int swz = (id & 7) * (F_GRID / 8) + (id >> 3);
    int b_blk = swz / F_NBLKN, n_blk = swz % F_NBLKN;
    int t = threadIdx.x;
    int n0 = n_blk * F_NPB + t * F_NT;
    int b0 = b_blk * F_BTILE;
    int ix[F_NT][4];
#pragma unroll
    for (int i = 0; i < 4; ++i) {
        int4 v = *reinterpret_cast<const int4*>(indices + i * NLUTS + n0);
        ix[0][i] = v.x; ix[1][i] = v.y; ix[2][i] = v.z; ix[3][i] = v.w;
    }
    float a[F_NT][16];
#pragma unroll
    for (int q = 0; q < F_NT; ++q) {
        int n = n0 + q; float p[16];
#pragma unroll
        for (int k = 0; k < 4; ++k) {
            float4 wv = *reinterpret_cast<const float4*>(w     + (size_t)n * 16 + k * 4);
            float4 cv = *reinterpret_cast<const float4*>(wcomp + (size_t)n * 16 + k * 4);
            p[15-(4*k+0)] = 1.f/(1.f+__expf(cv.x-wv.x));
            p[15-(4*k+1)] = 1.f/(1.f+__expf(cv.y-wv.y));
            p[15-(4*k+2)] = 1.f/(1.f+__expf(cv.z-wv.z));
            p[15-(4*k+3)] = 1.f/(1.f+__expf(cv.w-wv.w));
        }
#pragma unroll
        for (int s = 8; s >= 1; s >>= 1)
#pragma unroll
            for (int m = 0; m < 16; ++m)
                if ((m & s) == 0) { float t0 = p[m]; p[m] = p[m+s]; p[m+s] = t0 - p[m+s]; }
#pragma unroll
        for (int m = 0; m < 16; ++m) a[q][m] = p[m];
    }
    {
        const float* xrow = x + (size_t)b0 * IDIM;
#pragma unroll
        for (int k = 0; k < 4; ++k)
            *reinterpret_cast<float4*>(&xsf[0][(k*F_TPB+t)*4]) =
                *reinterpret_cast<const float4*>(xrow + (k*F_TPB+t)*4);
    }
    __syncthreads();
    for (int bi = 0; bi < F_BTILE; ++bi) {
        int cur = bi & 1; bool more = (bi + 1 < F_BTILE);
        float4 r[4];
        if (more) {
            const float* xrow = x + (size_t)(b0+bi+1) * IDIM;
#pragma unroll
            for (int k = 0; k < 4; ++k)
                r[k] = *reinterpret_cast<const float4*>(xrow + (k*F_TPB+t)*4);
        }
        float res[F_NT];
#pragma unroll
        for (int q = 0; q < F_NT; ++q) {
            float v0 = xsf[cur][ix[q][0]], v1 = xsf[cur][ix[q][1]];
            float v2 = xsf[cur][ix[q][2]], v3 = xsf[cur][ix[q][3]];
            float h0 = fmaf(v3,a[q][1],a[q][0]),  h1 = fmaf(v3,a[q][3],a[q][2]);
            float h2 = fmaf(v3,a[q][5],a[q][4]),  h3 = fmaf(v3,a[q][7],a[q][6]);
            float h4 = fmaf(v3,a[q][9],a[q][8]),  h5 = fmaf(v3,a[q][11],a[q][10]);
            float h6 = fmaf(v3,a[q][13],a[q][12]),h7 = fmaf(v3,a[q][15],a[q][14]);
            float g0 = fmaf(v2,h1,h0), g1 = fmaf(v2,h3,h2);
            float g2 = fmaf(v2,h5,h4), g3 = fmaf(v2,h7,h6);
            res[q] = fmaf(v0, fmaf(v1,g3,g2), fmaf(v1,g1,g0));
        }
        float4 o; o.x=res[0]; o.y=res[1]; o.z=res[2]; o.w=res[3];
        *reinterpret_cast<float4*>(out + (size_t)(b0+bi)*NLUTS + n0) = o;
        if (more) {
            int nxt = cur ^ 1;
#pragma unroll
            for (int k = 0; k < 4; ++k)
                *reinterpret_cast<float4*>(&xsf[nxt][(k*F_TPB+t)*4]) = r[k];
        }
        __syncthreads();
    }
}

extern "C" void kernel_launch(void* const* d_in, const int* in_sizes, int n_in,
                              void* d_out, int out_size, void* d_ws, size_t ws_size,
                              hipStream_t stream) {
    const float* x   = (const float*)d_in[0];
    const float* w   = (const float*)d_in[1];
    const float* wc  = (const float*)d_in[2];
    const int*   idx = (const int*)d_in[3];
    float*       out = (float*)d_out;

    if (ws_size >= (size_t)NLUTS * 16 * sizeof(float)) {
        float* cf = (float*)d_ws;
        coeff_kernel<<<dim3(NLUTS / 64), dim3(64), 0, stream>>>(w, wc, cf);
        lut_main<<<dim3(GRID), dim3(TPB), 0, stream>>>(x, cf, idx, out);
    } else {
        lut_fused<<<dim3(F_GRID), dim3(F_TPB), 0, stream>>>(x, w, wc, idx, out);
    }
}